// Round 1
// baseline (372.633 us; speedup 1.0000x reference)
//
#include <hip/hip_runtime.h>
#include <hip/hip_bf16.h>
#include <math.h>

#define W 512
#define H 512
#define HW 262144
#define NB 16

__device__ __forceinline__ int brev9(int x) { return (int)(__brev((unsigned)x) >> 23); }

// Block-wide min/max reduce (256 threads) + device-scope uint atomics.
// Valid for nonnegative floats (uint order == float order).
__device__ __forceinline__ void block_minmax_atomic(float vmin, float vmax,
                                                    unsigned* minU, unsigned* maxU) {
  #pragma unroll
  for (int o = 32; o; o >>= 1) {
    vmin = fminf(vmin, __shfl_xor(vmin, o));
    vmax = fmaxf(vmax, __shfl_xor(vmax, o));
  }
  __shared__ float smin[4], smax[4];
  int wid = threadIdx.x >> 6;
  int lane = threadIdx.x & 63;
  if (lane == 0) { smin[wid] = vmin; smax[wid] = vmax; }
  __syncthreads();
  if (threadIdx.x == 0) {
    float m = smin[0], M = smax[0];
    #pragma unroll
    for (int i = 1; i < 4; ++i) { m = fminf(m, smin[i]); M = fmaxf(M, smax[i]); }
    atomicMin(minU, __float_as_uint(m));
    atomicMax(maxU, __float_as_uint(M));
  }
  __syncthreads();  // protect smin/smax for a subsequent call
}

__global__ void k_init(unsigned* mm) {
  int t = threadIdx.x;
  if (t < 48) mm[t] = 0x7F800000u;      // min slots = +inf
  else if (t < 96) mm[t] = 0u;          // max slots = 0 (all maps nonneg)
}

__device__ __forceinline__ float gray_one(float r, float g, float b) {
  float R = fminf(fmaxf(fmaf(r, 0.229f, 0.485f), 0.f), 1.f) * 255.f;
  float G = fminf(fmaxf(fmaf(g, 0.224f, 0.456f), 0.f), 1.f) * 255.f;
  float B = fminf(fmaxf(fmaf(b, 0.225f, 0.406f), 0.f), 1.f) * 255.f;
  return fmaf(0.299f, R, fmaf(0.587f, G, 0.114f * B));
}

__global__ void k_gray(const float* __restrict__ x, float* __restrict__ gray) {
  int i4 = blockIdx.x * blockDim.x + threadIdx.x;   // 0..1048575
  int pix = i4 << 2;
  int b = pix >> 18;
  int hw = pix & (HW - 1);
  const float4 r4 = *(const float4*)(x + (((size_t)(b * 3 + 0)) << 18) + hw);
  const float4 g4 = *(const float4*)(x + (((size_t)(b * 3 + 1)) << 18) + hw);
  const float4 b4 = *(const float4*)(x + (((size_t)(b * 3 + 2)) << 18) + hw);
  float4 o;
  o.x = gray_one(r4.x, g4.x, b4.x);
  o.y = gray_one(r4.y, g4.y, b4.y);
  o.z = gray_one(r4.z, g4.z, b4.z);
  o.w = gray_one(r4.w, g4.w, b4.w);
  *(float4*)(gray + (((size_t)b) << 18) + hw) = o;
}

// Channels 1 (|laplacian|, zero-pad SAME) and 2 (blockiness, wraparound roll), fused.
__global__ void k_ch12(const float* __restrict__ gray, float* __restrict__ out, unsigned* mm) {
  int r = blockIdx.x, b = blockIdx.y, t = threadIdx.x;
  __shared__ float cur[W], prv[W], nxt[W];
  const float* gb = gray + (((size_t)b) << 18);
  int rp = (r + H - 1) & (H - 1);  // wrapped previous row (for dv)
  #pragma unroll
  for (int k = t; k < W; k += 256) {
    cur[k] = gb[r * W + k];
    prv[k] = gb[rp * W + k];
    nxt[k] = (r < H - 1) ? gb[(r + 1) * W + k] : 0.f;
  }
  __syncthreads();
  float mn1 = INFINITY, mx1 = -INFINITY, mn2 = INFINITY, mx2 = -INFINITY;
  float* o1 = out + (((size_t)(b * 3 + 1)) << 18) + r * W;
  float* o2 = out + (((size_t)(b * 3 + 2)) << 18) + r * W;
  #pragma unroll
  for (int k = t; k < W; k += 256) {
    float c = cur[k];
    float lf = (k > 0) ? cur[k - 1] : 0.f;
    float rt = (k < W - 1) ? cur[k + 1] : 0.f;
    float up = (r > 0) ? prv[k] : 0.f;       // laplacian: zero pad
    float dn = nxt[k];
    float lap = fabsf(lf + rt + up + dn - 4.f * c);
    o1[k] = lap;
    mn1 = fminf(mn1, lap); mx1 = fmaxf(mx1, lap);
    float dh = fabsf(c - cur[(k + W - 1) & (W - 1)]);  // roll: wrap
    float dv = fabsf(c - prv[k]);                      // roll: wrap
    float blk = (((k & 7) == 0) ? dh : 0.f) + (((r & 7) == 0) ? dv : 0.f);
    o2[k] = blk;
    mn2 = fminf(mn2, blk); mx2 = fmaxf(mx2, blk);
  }
  block_minmax_atomic(mn1, mx1, mm + (b * 3 + 1), mm + 48 + (b * 3 + 1));
  block_minmax_atomic(mn2, mx2, mm + (b * 3 + 2), mm + 48 + (b * 3 + 2));
}

// In-place radix-2 DIT 512-pt FFT in LDS; input pre-permuted (bit-reversed),
// output natural order. DIR=+1 forward (exp(-i...)), DIR=-1 inverse (exp(+i...)).
template <int DIR>
__device__ __forceinline__ void fft512(float* sre, float* sim, int t) {
  #pragma unroll
  for (int s = 1; s <= 9; ++s) {
    int half = 1 << (s - 1);
    __syncthreads();
    int j = t & (half - 1);
    int i0 = ((t >> (s - 1)) << s) + j;
    int i1 = i0 + half;
    float ang = (float)DIR * -6.283185307179586f * (float)j / (float)(1 << s);
    float sn, cs;
    __sincosf(ang, &sn, &cs);
    float ur = sre[i0], ui = sim[i0];
    float vr = sre[i1], vi = sim[i1];
    float tr = fmaf(vr, cs, -vi * sn);
    float ti = fmaf(vr, sn, vi * cs);
    sre[i0] = ur + tr; sim[i0] = ui + ti;
    sre[i1] = ur - tr; sim[i1] = ui - ti;
  }
  __syncthreads();
}

// 8 columns per block in LDS (pitch 9 to dodge bank conflicts), 32 threads/column.
template <int DIR>
__device__ __forceinline__ void fft512x8(float* sre, float* sim, int c, int tc) {
  #pragma unroll
  for (int s = 1; s <= 9; ++s) {
    int half = 1 << (s - 1);
    __syncthreads();
    #pragma unroll
    for (int bb = 0; bb < 8; ++bb) {
      int bf = tc + (bb << 5);
      int j = bf & (half - 1);
      int i0 = ((bf >> (s - 1)) << s) + j;
      int i1 = i0 + half;
      float ang = (float)DIR * -6.283185307179586f * (float)j / (float)(1 << s);
      float sn, cs;
      __sincosf(ang, &sn, &cs);
      int a0 = i0 * 9 + c, a1 = i1 * 9 + c;
      float ur = sre[a0], ui = sim[a0];
      float vr = sre[a1], vi = sim[a1];
      float tr = fmaf(vr, cs, -vi * sn);
      float ti = fmaf(vr, sn, vi * cs);
      sre[a0] = ur + tr; sim[a0] = ui + ti;
      sre[a1] = ur - tr; sim[a1] = ui - ti;
    }
  }
  __syncthreads();
}

__global__ void k_rowfft(const float* __restrict__ gray, float2* __restrict__ C) {
  int r = blockIdx.x, b = blockIdx.y, t = threadIdx.x;
  __shared__ float sre[512], sim[512];
  const float* g = gray + (((size_t)b) << 18) + r * W;
  #pragma unroll
  for (int k = t; k < 512; k += 256) {
    int kr = brev9(k);
    sre[kr] = g[k]; sim[kr] = 0.f;
  }
  fft512<1>(sre, sim, t);
  float2* Crow = C + (((size_t)b) << 18) + r * W;
  #pragma unroll
  for (int k = t; k < 512; k += 256) Crow[k] = make_float2(sre[k], sim[k]);
}

// Column forward FFT (in-place on C) + logmag epilogue.
__global__ void k_colfft_fwd(float2* __restrict__ C, float* __restrict__ L) {
  int b = blockIdx.y, col0 = blockIdx.x << 3, t = threadIdx.x;
  __shared__ float sre[512 * 9], sim[512 * 9];
  float2* Cb = C + (((size_t)b) << 18);
  int c = t & 7, q = t >> 3;
  #pragma unroll
  for (int it = 0; it < 16; ++it) {
    int r = (it << 5) + q;
    float2 v = Cb[r * W + col0 + c];
    int rr = brev9(r);
    sre[rr * 9 + c] = v.x; sim[rr * 9 + c] = v.y;
  }
  fft512x8<1>(sre, sim, t >> 5, t & 31);
  float* Lb = L + (((size_t)b) << 18);
  #pragma unroll
  for (int it = 0; it < 16; ++it) {
    int r = (it << 5) + q;
    float re = sre[r * 9 + c], im = sim[r * 9 + c];
    Cb[r * W + col0 + c] = make_float2(re, im);
    Lb[r * W + col0 + c] = logf(sqrtf(fmaf(re, re, im * im)) + 1e-8f);
  }
}

// Build G = exp(resid) * e^{i*phase} = C * exp(resid)/|C| inline, then inverse row FFT.
__global__ void k_rowifft_g(float2* __restrict__ C, const float* __restrict__ L) {
  int r = blockIdx.x, b = blockIdx.y, t = threadIdx.x;
  __shared__ float sre[512], sim[512], l0[512], lm[512], lp[512];
  const float* Lb = L + (((size_t)b) << 18);
  #pragma unroll
  for (int k = t; k < 512; k += 256) {
    l0[k] = Lb[r * W + k];
    lm[k] = (r > 0) ? Lb[(r - 1) * W + k] : 0.f;
    lp[k] = (r < H - 1) ? Lb[(r + 1) * W + k] : 0.f;
  }
  __syncthreads();
  float2* Crow = C + (((size_t)b) << 18) + r * W;
  #pragma unroll
  for (int k = t; k < 512; k += 256) {
    float sum = lm[k] + l0[k] + lp[k];
    if (k > 0)     sum += lm[k - 1] + l0[k - 1] + lp[k - 1];
    if (k < W - 1) sum += lm[k + 1] + l0[k + 1] + lp[k + 1];
    float resid = l0[k] - sum * (1.f / 9.f);
    float2 cv = Crow[k];
    float mag = sqrtf(fmaf(cv.x, cv.x, cv.y * cv.y));
    float er = __expf(resid);
    float gr, gi;
    if (mag > 1e-30f) { float tt = er / mag; gr = cv.x * tt; gi = cv.y * tt; }
    else { gr = er; gi = 0.f; }  // angle(0)=0 per reference
    int kr = brev9(k);
    sre[kr] = gr; sim[kr] = gi;
  }
  fft512<-1>(sre, sim, t);
  #pragma unroll
  for (int k = t; k < 512; k += 256)
    Crow[k] = make_float2(sre[k] * (1.f / 512.f), sim[k] * (1.f / 512.f));
}

// Inverse column FFT + sal=|.|^2 epilogue straight to out channel 0 + min/max.
__global__ void k_colifft_sal(const float2* __restrict__ C, float* __restrict__ out, unsigned* mm) {
  int b = blockIdx.y, col0 = blockIdx.x << 3, t = threadIdx.x;
  __shared__ float sre[512 * 9], sim[512 * 9];
  const float2* Cb = C + (((size_t)b) << 18);
  int c = t & 7, q = t >> 3;
  #pragma unroll
  for (int it = 0; it < 16; ++it) {
    int r = (it << 5) + q;
    float2 v = Cb[r * W + col0 + c];
    int rr = brev9(r);
    sre[rr * 9 + c] = v.x; sim[rr * 9 + c] = v.y;
  }
  fft512x8<-1>(sre, sim, t >> 5, t & 31);
  float* ob = out + (((size_t)(b * 3 + 0)) << 18);
  float mn = INFINITY, mx = -INFINITY;
  #pragma unroll
  for (int it = 0; it < 16; ++it) {
    int r = (it << 5) + q;
    float re = sre[r * 9 + c], im = sim[r * 9 + c];
    // row pass carried 1/512; this pass contributes the other 1/512 -> (1/512)^2 on |.|^2
    float sal = fmaf(re, re, im * im) * 3.814697265625e-6f;
    ob[r * W + col0 + c] = sal;
    mn = fminf(mn, sal); mx = fmaxf(mx, sal);
  }
  block_minmax_atomic(mn, mx, mm + b * 3, mm + 48 + b * 3);
}

__global__ void k_norm(float* __restrict__ out, const unsigned* __restrict__ mm) {
  int i = blockIdx.x * blockDim.x + threadIdx.x;  // 0..3145727
  size_t base = ((size_t)i) << 2;
  int map = (int)(base >> 18);                    // 0..47 == b*3+ch
  float mn = __uint_as_float(mm[map]);
  float mx = __uint_as_float(mm[48 + map]);
  float rng = mx - mn;
  float4 v = *(float4*)(out + base);
  float4 o;
  if (rng < 1e-8f) {
    o = make_float4(0.f, 0.f, 0.f, 0.f);
  } else {
    float inv = 1.f / rng;
    o.x = (v.x - mn) * inv;
    o.y = (v.y - mn) * inv;
    o.z = (v.z - mn) * inv;
    o.w = (v.w - mn) * inv;
  }
  *(float4*)(out + base) = o;
}

extern "C" void kernel_launch(void* const* d_in, const int* in_sizes, int n_in,
                              void* d_out, int out_size, void* d_ws, size_t ws_size,
                              hipStream_t stream) {
  const float* x = (const float*)d_in[0];
  float* out = (float*)d_out;

  // workspace layout: gray (16.8MB) | C complex (33.6MB) | L logmag (16.8MB) | minmax (384B)
  float* gray = (float*)d_ws;
  float2* C = (float2*)((char*)d_ws + (size_t)NB * HW * sizeof(float));
  float* L = (float*)((char*)C + (size_t)NB * HW * sizeof(float2));
  unsigned* mm = (unsigned*)((char*)L + (size_t)NB * HW * sizeof(float));

  k_init<<<1, 96, 0, stream>>>(mm);
  k_gray<<<4096, 256, 0, stream>>>(x, gray);
  k_ch12<<<dim3(H, NB), 256, 0, stream>>>(gray, out, mm);
  k_rowfft<<<dim3(H, NB), 256, 0, stream>>>(gray, C);
  k_colfft_fwd<<<dim3(W / 8, NB), 256, 0, stream>>>(C, L);
  k_rowifft_g<<<dim3(H, NB), 256, 0, stream>>>(C, L);
  k_colifft_sal<<<dim3(W / 8, NB), 256, 0, stream>>>(C, out, mm);
  k_norm<<<12288, 256, 0, stream>>>(out, mm);
}

// Round 3
// 241.120 us; speedup vs baseline: 1.5454x; 1.5454x over previous
//
#include <hip/hip_runtime.h>
#include <hip/hip_bf16.h>
#include <math.h>

#define W 512
#define H 512
#define HW 262144
#define NB 16

__device__ __forceinline__ int brev9(int x) { return (int)(__brev((unsigned)x) >> 23); }

// Block-wide min/max reduce (256 threads) + device-scope uint atomics.
// Valid for nonnegative floats (uint order == float order).
__device__ __forceinline__ void block_minmax_atomic(float vmin, float vmax,
                                                    unsigned* minU, unsigned* maxU) {
  #pragma unroll
  for (int o = 32; o; o >>= 1) {
    vmin = fminf(vmin, __shfl_xor(vmin, o));
    vmax = fmaxf(vmax, __shfl_xor(vmax, o));
  }
  __shared__ float smin[4], smax[4];
  int wid = threadIdx.x >> 6;
  int lane = threadIdx.x & 63;
  if (lane == 0) { smin[wid] = vmin; smax[wid] = vmax; }
  __syncthreads();
  if (threadIdx.x == 0) {
    float m = smin[0], M = smax[0];
    #pragma unroll
    for (int i = 1; i < 4; ++i) { m = fminf(m, smin[i]); M = fmaxf(M, smax[i]); }
    atomicMin(minU, __float_as_uint(m));
    atomicMax(maxU, __float_as_uint(M));
  }
  __syncthreads();  // protect smin/smax for a subsequent call
}

__global__ void k_init(unsigned* mm) {
  int t = threadIdx.x;
  if (t < 48) mm[t] = 0x7F800000u;      // min slots = +inf
  else if (t < 96) mm[t] = 0u;          // max slots = 0 (all maps nonneg)
}

__device__ __forceinline__ float gray_one(float r, float g, float b) {
  float R = fminf(fmaxf(fmaf(r, 0.229f, 0.485f), 0.f), 1.f) * 255.f;
  float G = fminf(fmaxf(fmaf(g, 0.224f, 0.456f), 0.f), 1.f) * 255.f;
  float B = fminf(fmaxf(fmaf(b, 0.225f, 0.406f), 0.f), 1.f) * 255.f;
  return fmaf(0.299f, R, fmaf(0.587f, G, 0.114f * B));
}

__global__ void k_gray(const float* __restrict__ x, float* __restrict__ gray) {
  int i4 = blockIdx.x * blockDim.x + threadIdx.x;   // 0..1048575
  int pix = i4 << 2;
  int b = pix >> 18;
  int hw = pix & (HW - 1);
  const float4 r4 = *(const float4*)(x + (((size_t)(b * 3 + 0)) << 18) + hw);
  const float4 g4 = *(const float4*)(x + (((size_t)(b * 3 + 1)) << 18) + hw);
  const float4 b4 = *(const float4*)(x + (((size_t)(b * 3 + 2)) << 18) + hw);
  float4 o;
  o.x = gray_one(r4.x, g4.x, b4.x);
  o.y = gray_one(r4.y, g4.y, b4.y);
  o.z = gray_one(r4.z, g4.z, b4.z);
  o.w = gray_one(r4.w, g4.w, b4.w);
  *(float4*)(gray + (((size_t)b) << 18) + hw) = o;
}

// Channels 1 (|laplacian|, zero-pad SAME) and 2 (blockiness, wraparound roll), fused.
// One 32-row slab per block: grid (16 slabs, 16 images) = 256 blocks total, so
// the tail atomics are ~16 per address instead of 512 (the old 8192-block
// version spent ~149us serializing ~32K same-cache-line L2 atomics).
__global__ void k_ch12(const float* __restrict__ gray, float* __restrict__ out, unsigned* mm) {
  int slab = blockIdx.x, b = blockIdx.y, t = threadIdx.x;
  const float* gb = gray + (((size_t)b) << 18);
  float* o1 = out + (((size_t)(b * 3 + 1)) << 18);
  float* o2 = out + (((size_t)(b * 3 + 2)) << 18);
  float mn1 = INFINITY, mx1 = -INFINITY, mn2 = INFINITY, mx2 = -INFINITY;
  // 32 rows per slab, 128 float4 per row
  for (int i4 = t; i4 < 32 * 128; i4 += 256) {
    int r = (slab << 5) + (i4 >> 7);
    int k4 = (i4 & 127) << 2;
    const float* row = gb + r * W;
    float4 c4 = *(const float4*)(row + k4);
    float s_lfw = row[(k4 + W - 1) & (W - 1)];          // wrapped left of element 0
    float s_rt  = (k4 < W - 4) ? row[k4 + 4] : 0.f;     // right of element 3 (zero-pad)
    float4 up4 = (r > 0)     ? *(const float4*)(gb + (r - 1) * W + k4) : make_float4(0.f, 0.f, 0.f, 0.f);
    float4 dn4 = (r < H - 1) ? *(const float4*)(gb + (r + 1) * W + k4) : make_float4(0.f, 0.f, 0.f, 0.f);
    float c[4]  = {c4.x, c4.y, c4.z, c4.w};
    float up[4] = {up4.x, up4.y, up4.z, up4.w};
    float dn[4] = {dn4.x, dn4.y, dn4.z, dn4.w};
    float lap[4], blk[4];
    #pragma unroll
    for (int e = 0; e < 4; ++e) {
      float lf = (e == 0) ? ((k4 > 0) ? s_lfw : 0.f) : c[e - 1];
      float rt = (e == 3) ? s_rt : c[e + 1];
      lap[e] = fabsf(lf + rt + up[e] + dn[e] - 4.f * c[e]);
      mn1 = fminf(mn1, lap[e]); mx1 = fmaxf(mx1, lap[e]);
    }
    bool rowb = ((r & 7) == 0);
    float pv[4] = {0.f, 0.f, 0.f, 0.f};
    if (rowb) {
      int rp = (r + H - 1) & (H - 1);                   // wrapped previous row (roll)
      float4 p4 = *(const float4*)(gb + rp * W + k4);
      pv[0] = p4.x; pv[1] = p4.y; pv[2] = p4.z; pv[3] = p4.w;
    }
    #pragma unroll
    for (int e = 0; e < 4; ++e) {
      float v = 0.f;
      if (e == 0 && ((k4 & 7) == 0)) v += fabsf(c[0] - s_lfw);  // dh at k%8==0 (wrap)
      if (rowb) v += fabsf(c[e] - pv[e]);                        // dv at r%8==0 (wrap)
      blk[e] = v;
      mn2 = fminf(mn2, v); mx2 = fmaxf(mx2, v);
    }
    *(float4*)(o1 + r * W + k4) = make_float4(lap[0], lap[1], lap[2], lap[3]);
    *(float4*)(o2 + r * W + k4) = make_float4(blk[0], blk[1], blk[2], blk[3]);
  }
  block_minmax_atomic(mn1, mx1, mm + (b * 3 + 1), mm + 48 + (b * 3 + 1));
  block_minmax_atomic(mn2, mx2, mm + (b * 3 + 2), mm + 48 + (b * 3 + 2));
}

// In-place radix-2 DIT 512-pt FFT in LDS; input pre-permuted (bit-reversed),
// output natural order. DIR=+1 forward (exp(-i...)), DIR=-1 inverse (exp(+i...)).
template <int DIR>
__device__ __forceinline__ void fft512(float* sre, float* sim, int t) {
  #pragma unroll
  for (int s = 1; s <= 9; ++s) {
    int half = 1 << (s - 1);
    __syncthreads();
    int j = t & (half - 1);
    int i0 = ((t >> (s - 1)) << s) + j;
    int i1 = i0 + half;
    float ang = (float)DIR * -6.283185307179586f * (float)j / (float)(1 << s);
    float sn, cs;
    __sincosf(ang, &sn, &cs);
    float ur = sre[i0], ui = sim[i0];
    float vr = sre[i1], vi = sim[i1];
    float tr = fmaf(vr, cs, -vi * sn);
    float ti = fmaf(vr, sn, vi * cs);
    sre[i0] = ur + tr; sim[i0] = ui + ti;
    sre[i1] = ur - tr; sim[i1] = ui - ti;
  }
  __syncthreads();
}

// 8 columns per block in LDS (pitch 9 to dodge bank conflicts), 32 threads/column.
template <int DIR>
__device__ __forceinline__ void fft512x8(float* sre, float* sim, int c, int tc) {
  #pragma unroll
  for (int s = 1; s <= 9; ++s) {
    int half = 1 << (s - 1);
    __syncthreads();
    #pragma unroll
    for (int bb = 0; bb < 8; ++bb) {
      int bf = tc + (bb << 5);
      int j = bf & (half - 1);
      int i0 = ((bf >> (s - 1)) << s) + j;
      int i1 = i0 + half;
      float ang = (float)DIR * -6.283185307179586f * (float)j / (float)(1 << s);
      float sn, cs;
      __sincosf(ang, &sn, &cs);
      int a0 = i0 * 9 + c, a1 = i1 * 9 + c;
      float ur = sre[a0], ui = sim[a0];
      float vr = sre[a1], vi = sim[a1];
      float tr = fmaf(vr, cs, -vi * sn);
      float ti = fmaf(vr, sn, vi * cs);
      sre[a0] = ur + tr; sim[a0] = ui + ti;
      sre[a1] = ur - tr; sim[a1] = ui - ti;
    }
  }
  __syncthreads();
}

__global__ void k_rowfft(const float* __restrict__ gray, float2* __restrict__ C) {
  int r = blockIdx.x, b = blockIdx.y, t = threadIdx.x;
  __shared__ float sre[512], sim[512];
  const float* g = gray + (((size_t)b) << 18) + r * W;
  #pragma unroll
  for (int k = t; k < 512; k += 256) {
    int kr = brev9(k);
    sre[kr] = g[k]; sim[kr] = 0.f;
  }
  fft512<1>(sre, sim, t);
  float2* Crow = C + (((size_t)b) << 18) + r * W;
  #pragma unroll
  for (int k = t; k < 512; k += 256) Crow[k] = make_float2(sre[k], sim[k]);
}

// Column forward FFT (in-place on C) + logmag epilogue.
__global__ void k_colfft_fwd(float2* __restrict__ C, float* __restrict__ L) {
  int b = blockIdx.y, col0 = blockIdx.x << 3, t = threadIdx.x;
  __shared__ float sre[512 * 9], sim[512 * 9];
  float2* Cb = C + (((size_t)b) << 18);
  int c = t & 7, q = t >> 3;
  #pragma unroll
  for (int it = 0; it < 16; ++it) {
    int r = (it << 5) + q;
    float2 v = Cb[r * W + col0 + c];
    int rr = brev9(r);
    sre[rr * 9 + c] = v.x; sim[rr * 9 + c] = v.y;
  }
  fft512x8<1>(sre, sim, t >> 5, t & 31);
  float* Lb = L + (((size_t)b) << 18);
  #pragma unroll
  for (int it = 0; it < 16; ++it) {
    int r = (it << 5) + q;
    float re = sre[r * 9 + c], im = sim[r * 9 + c];
    Cb[r * W + col0 + c] = make_float2(re, im);
    Lb[r * W + col0 + c] = logf(sqrtf(fmaf(re, re, im * im)) + 1e-8f);
  }
}

// Build G = exp(resid) * e^{i*phase} = C * exp(resid)/|C| inline, then inverse row FFT.
__global__ void k_rowifft_g(float2* __restrict__ C, const float* __restrict__ L) {
  int r = blockIdx.x, b = blockIdx.y, t = threadIdx.x;
  __shared__ float sre[512], sim[512], l0[512], lm[512], lp[512];
  const float* Lb = L + (((size_t)b) << 18);
  #pragma unroll
  for (int k = t; k < 512; k += 256) {
    l0[k] = Lb[r * W + k];
    lm[k] = (r > 0) ? Lb[(r - 1) * W + k] : 0.f;
    lp[k] = (r < H - 1) ? Lb[(r + 1) * W + k] : 0.f;
  }
  __syncthreads();
  float2* Crow = C + (((size_t)b) << 18) + r * W;
  #pragma unroll
  for (int k = t; k < 512; k += 256) {
    float sum = lm[k] + l0[k] + lp[k];
    if (k > 0)     sum += lm[k - 1] + l0[k - 1] + lp[k - 1];
    if (k < W - 1) sum += lm[k + 1] + l0[k + 1] + lp[k + 1];
    float resid = l0[k] - sum * (1.f / 9.f);
    float2 cv = Crow[k];
    float mag = sqrtf(fmaf(cv.x, cv.x, cv.y * cv.y));
    float er = __expf(resid);
    float gr, gi;
    if (mag > 1e-30f) { float tt = er / mag; gr = cv.x * tt; gi = cv.y * tt; }
    else { gr = er; gi = 0.f; }  // angle(0)=0 per reference
    int kr = brev9(k);
    sre[kr] = gr; sim[kr] = gi;
  }
  fft512<-1>(sre, sim, t);
  #pragma unroll
  for (int k = t; k < 512; k += 256)
    Crow[k] = make_float2(sre[k] * (1.f / 512.f), sim[k] * (1.f / 512.f));
}

// Inverse column FFT + sal=|.|^2 epilogue straight to out channel 0 + min/max.
__global__ void k_colifft_sal(const float2* __restrict__ C, float* __restrict__ out, unsigned* mm) {
  int b = blockIdx.y, col0 = blockIdx.x << 3, t = threadIdx.x;
  __shared__ float sre[512 * 9], sim[512 * 9];
  const float2* Cb = C + (((size_t)b) << 18);
  int c = t & 7, q = t >> 3;
  #pragma unroll
  for (int it = 0; it < 16; ++it) {
    int r = (it << 5) + q;
    float2 v = Cb[r * W + col0 + c];
    int rr = brev9(r);
    sre[rr * 9 + c] = v.x; sim[rr * 9 + c] = v.y;
  }
  fft512x8<-1>(sre, sim, t >> 5, t & 31);
  float* ob = out + (((size_t)(b * 3 + 0)) << 18);
  float mn = INFINITY, mx = -INFINITY;
  #pragma unroll
  for (int it = 0; it < 16; ++it) {
    int r = (it << 5) + q;
    float re = sre[r * 9 + c], im = sim[r * 9 + c];
    // row pass carried 1/512; this pass contributes the other 1/512 -> (1/512)^2 on |.|^2
    float sal = fmaf(re, re, im * im) * 3.814697265625e-6f;
    ob[r * W + col0 + c] = sal;
    mn = fminf(mn, sal); mx = fmaxf(mx, sal);
  }
  block_minmax_atomic(mn, mx, mm + b * 3, mm + 48 + b * 3);
}

__global__ void k_norm(float* __restrict__ out, const unsigned* __restrict__ mm) {
  int i = blockIdx.x * blockDim.x + threadIdx.x;  // 0..3145727
  size_t base = ((size_t)i) << 2;
  int map = (int)(base >> 18);                    // 0..47 == b*3+ch
  float mn = __uint_as_float(mm[map]);
  float mx = __uint_as_float(mm[48 + map]);
  float rng = mx - mn;
  float4 v = *(float4*)(out + base);
  float4 o;
  if (rng < 1e-8f) {
    o = make_float4(0.f, 0.f, 0.f, 0.f);
  } else {
    float inv = 1.f / rng;
    o.x = (v.x - mn) * inv;
    o.y = (v.y - mn) * inv;
    o.z = (v.z - mn) * inv;
    o.w = (v.w - mn) * inv;
  }
  *(float4*)(out + base) = o;
}

extern "C" void kernel_launch(void* const* d_in, const int* in_sizes, int n_in,
                              void* d_out, int out_size, void* d_ws, size_t ws_size,
                              hipStream_t stream) {
  const float* x = (const float*)d_in[0];
  float* out = (float*)d_out;

  // workspace layout: gray (16.8MB) | C complex (33.6MB) | L logmag (16.8MB) | minmax (384B)
  float* gray = (float*)d_ws;
  float2* C = (float2*)((char*)d_ws + (size_t)NB * HW * sizeof(float));
  float* L = (float*)((char*)C + (size_t)NB * HW * sizeof(float2));
  unsigned* mm = (unsigned*)((char*)L + (size_t)NB * HW * sizeof(float));

  k_init<<<1, 96, 0, stream>>>(mm);
  k_gray<<<4096, 256, 0, stream>>>(x, gray);
  k_ch12<<<dim3(16, NB), 256, 0, stream>>>(gray, out, mm);
  k_rowfft<<<dim3(H, NB), 256, 0, stream>>>(gray, C);
  k_colfft_fwd<<<dim3(W / 8, NB), 256, 0, stream>>>(C, L);
  k_rowifft_g<<<dim3(H, NB), 256, 0, stream>>>(C, L);
  k_colifft_sal<<<dim3(W / 8, NB), 256, 0, stream>>>(C, out, mm);
  k_norm<<<12288, 256, 0, stream>>>(out, mm);
}

// Round 5
// 233.493 us; speedup vs baseline: 1.5959x; 1.0327x over previous
//
#include <hip/hip_runtime.h>
#include <hip/hip_bf16.h>
#include <math.h>

#define W 512
#define H 512
#define HW 262144
#define NB 16

__device__ __forceinline__ int brev9(int x) { return (int)(__brev((unsigned)x) >> 23); }

// Block-wide min/max reduce (256 threads) + device-scope uint atomics.
// Valid for nonnegative floats (uint order == float order).
__device__ __forceinline__ void block_minmax_atomic(float vmin, float vmax,
                                                    unsigned* minU, unsigned* maxU) {
  #pragma unroll
  for (int o = 32; o; o >>= 1) {
    vmin = fminf(vmin, __shfl_xor(vmin, o));
    vmax = fmaxf(vmax, __shfl_xor(vmax, o));
  }
  __shared__ float smin[4], smax[4];
  int wid = threadIdx.x >> 6;
  int lane = threadIdx.x & 63;
  if (lane == 0) { smin[wid] = vmin; smax[wid] = vmax; }
  __syncthreads();
  if (threadIdx.x == 0) {
    float m = smin[0], M = smax[0];
    #pragma unroll
    for (int i = 1; i < 4; ++i) { m = fminf(m, smin[i]); M = fmaxf(M, smax[i]); }
    atomicMin(minU, __float_as_uint(m));
    atomicMax(maxU, __float_as_uint(M));
  }
  __syncthreads();  // protect smin/smax for a subsequent call
}

__global__ void k_init(unsigned* mm) {
  int t = threadIdx.x;
  if (t < 48) mm[t] = 0x7F800000u;      // min slots = +inf
  else if (t < 96) mm[t] = 0u;          // max slots = 0 (all maps nonneg)
}

__device__ __forceinline__ float gray_one(float r, float g, float b) {
  float R = fminf(fmaxf(fmaf(r, 0.229f, 0.485f), 0.f), 1.f) * 255.f;
  float G = fminf(fmaxf(fmaf(g, 0.224f, 0.456f), 0.f), 1.f) * 255.f;
  float B = fminf(fmaxf(fmaf(b, 0.225f, 0.406f), 0.f), 1.f) * 255.f;
  return fmaf(0.299f, R, fmaf(0.587f, G, 0.114f * B));
}

// Build the 512-pt twiddle table: tw[k] = (cos, sin)(-2*pi*k/512), k=0..255.
// Visibility is covered by the barrier at the top of FFT stage 1.
__device__ __forceinline__ void tw_init(float2* tw, int t) {
  if (t < 256) {
    float sn, cs;
    __sincosf(-6.283185307179586f * (float)t * (1.f / 512.f), &sn, &cs);
    tw[t] = make_float2(cs, sn);
  }
}

// In-place radix-2 DIT 512-pt FFT in LDS; input pre-permuted (bit-reversed),
// output natural order. DIR=+1 forward, DIR=-1 inverse (conjugated twiddles).
// Conservative sync: barrier at top of EVERY stage + trailing barrier.
// (Round-4's wave-locality sync elimination diverged under graph replay;
// this is the round-3-proven structure with table twiddles.)
template <int DIR>
__device__ __forceinline__ void fft512_tw(float* sre, float* sim, const float2* tw, int t) {
  #pragma unroll
  for (int s = 1; s <= 9; ++s) {
    __syncthreads();
    int half = 1 << (s - 1);
    int j = t & (half - 1);
    int i0 = ((t >> (s - 1)) << s) + j;
    int i1 = i0 + half;
    float2 w = tw[j << (9 - s)];
    float cs = w.x;
    float sn = (DIR > 0) ? w.y : -w.y;
    float ur = sre[i0], ui = sim[i0];
    float vr = sre[i1], vi = sim[i1];
    float tr = fmaf(vr, cs, -vi * sn);
    float ti = fmaf(vr, sn, vi * cs);
    sre[i0] = ur + tr; sim[i0] = ui + ti;
    sre[i1] = ur - tr; sim[i1] = ui - ti;
  }
  __syncthreads();
}

// 8 columns per block in LDS (pitch 9 to dodge bank conflicts), 32 threads per
// column, 8 butterflies per thread per stage. Conservative per-stage barriers.
template <int DIR>
__device__ __forceinline__ void fft512x8_tw(float* sre, float* sim, const float2* tw,
                                            int c, int tc) {
  #pragma unroll
  for (int s = 1; s <= 9; ++s) {
    __syncthreads();
    int half = 1 << (s - 1);
    #pragma unroll
    for (int bb = 0; bb < 8; ++bb) {
      int bf = tc + (bb << 5);
      int j = bf & (half - 1);
      int i0 = ((bf >> (s - 1)) << s) + j;
      int i1 = i0 + half;
      float2 w = tw[j << (9 - s)];
      float cs = w.x;
      float sn = (DIR > 0) ? w.y : -w.y;
      int a0 = i0 * 9 + c, a1 = i1 * 9 + c;
      float ur = sre[a0], ui = sim[a0];
      float vr = sre[a1], vi = sim[a1];
      float tr = fmaf(vr, cs, -vi * sn);
      float ti = fmaf(vr, sn, vi * cs);
      sre[a0] = ur + tr; sim[a0] = ui + ti;
      sre[a1] = ur - tr; sim[a1] = ui - ti;
    }
  }
  __syncthreads();
}

// Fused: gray conversion (reads x) + row forward FFT. Writes gray (for k_ch12)
// and the row spectrum C.
__global__ void k_rowfft(const float* __restrict__ x, float* __restrict__ gray,
                         float2* __restrict__ C) {
  int r = blockIdx.x, b = blockIdx.y, t = threadIdx.x;
  __shared__ float sre[512], sim[512];
  __shared__ float2 tw[256];
  tw_init(tw, t);
  const float* xr = x + (((size_t)(b * 3 + 0)) << 18) + r * W;
  const float* xg = x + (((size_t)(b * 3 + 1)) << 18) + r * W;
  const float* xb = x + (((size_t)(b * 3 + 2)) << 18) + r * W;
  float* gr = gray + (((size_t)b) << 18) + r * W;
  #pragma unroll
  for (int k = t; k < 512; k += 256) {
    float g = gray_one(xr[k], xg[k], xb[k]);
    gr[k] = g;
    int kr = brev9(k);
    sre[kr] = g; sim[kr] = 0.f;
  }
  fft512_tw<1>(sre, sim, tw, t);
  float2* Crow = C + (((size_t)b) << 18) + r * W;
  #pragma unroll
  for (int k = t; k < 512; k += 256) Crow[k] = make_float2(sre[k], sim[k]);
}

// Channels 1 (|laplacian|, zero-pad SAME) and 2 (blockiness, wraparound roll), fused.
// One 32-row slab per block: 256 blocks total keeps tail atomics ~16/address.
__global__ void k_ch12(const float* __restrict__ gray, float* __restrict__ out, unsigned* mm) {
  int slab = blockIdx.x, b = blockIdx.y, t = threadIdx.x;
  const float* gb = gray + (((size_t)b) << 18);
  float* o1 = out + (((size_t)(b * 3 + 1)) << 18);
  float* o2 = out + (((size_t)(b * 3 + 2)) << 18);
  float mn1 = INFINITY, mx1 = -INFINITY, mn2 = INFINITY, mx2 = -INFINITY;
  for (int i4 = t; i4 < 32 * 128; i4 += 256) {
    int r = (slab << 5) + (i4 >> 7);
    int k4 = (i4 & 127) << 2;
    const float* row = gb + r * W;
    float4 c4 = *(const float4*)(row + k4);
    float s_lfw = row[(k4 + W - 1) & (W - 1)];          // wrapped left of element 0
    float s_rt  = (k4 < W - 4) ? row[k4 + 4] : 0.f;     // right of element 3 (zero-pad)
    float4 up4 = (r > 0)     ? *(const float4*)(gb + (r - 1) * W + k4) : make_float4(0.f, 0.f, 0.f, 0.f);
    float4 dn4 = (r < H - 1) ? *(const float4*)(gb + (r + 1) * W + k4) : make_float4(0.f, 0.f, 0.f, 0.f);
    float c[4]  = {c4.x, c4.y, c4.z, c4.w};
    float up[4] = {up4.x, up4.y, up4.z, up4.w};
    float dn[4] = {dn4.x, dn4.y, dn4.z, dn4.w};
    float lap[4], blk[4];
    #pragma unroll
    for (int e = 0; e < 4; ++e) {
      float lf = (e == 0) ? ((k4 > 0) ? s_lfw : 0.f) : c[e - 1];
      float rt = (e == 3) ? s_rt : c[e + 1];
      lap[e] = fabsf(lf + rt + up[e] + dn[e] - 4.f * c[e]);
      mn1 = fminf(mn1, lap[e]); mx1 = fmaxf(mx1, lap[e]);
    }
    bool rowb = ((r & 7) == 0);
    float pv[4] = {0.f, 0.f, 0.f, 0.f};
    if (rowb) {
      int rp = (r + H - 1) & (H - 1);                   // wrapped previous row (roll)
      float4 p4 = *(const float4*)(gb + rp * W + k4);
      pv[0] = p4.x; pv[1] = p4.y; pv[2] = p4.z; pv[3] = p4.w;
    }
    #pragma unroll
    for (int e = 0; e < 4; ++e) {
      float v = 0.f;
      if (e == 0 && ((k4 & 7) == 0)) v += fabsf(c[0] - s_lfw);  // dh at k%8==0 (wrap)
      if (rowb) v += fabsf(c[e] - pv[e]);                        // dv at r%8==0 (wrap)
      blk[e] = v;
      mn2 = fminf(mn2, v); mx2 = fmaxf(mx2, v);
    }
    *(float4*)(o1 + r * W + k4) = make_float4(lap[0], lap[1], lap[2], lap[3]);
    *(float4*)(o2 + r * W + k4) = make_float4(blk[0], blk[1], blk[2], blk[3]);
  }
  block_minmax_atomic(mn1, mx1, mm + (b * 3 + 1), mm + 48 + (b * 3 + 1));
  block_minmax_atomic(mn2, mx2, mm + (b * 3 + 2), mm + 48 + (b * 3 + 2));
}

// Column forward FFT (in-place on C) + logmag epilogue.
__global__ void k_colfft_fwd(float2* __restrict__ C, float* __restrict__ L) {
  int b = blockIdx.y, col0 = blockIdx.x << 3, t = threadIdx.x;
  __shared__ float sre[512 * 9], sim[512 * 9];
  __shared__ float2 tw[256];
  tw_init(tw, t);
  float2* Cb = C + (((size_t)b) << 18);
  int c = t & 7, q = t >> 3;
  #pragma unroll
  for (int it = 0; it < 16; ++it) {
    int r = (it << 5) + q;
    float2 v = Cb[r * W + col0 + c];
    int rr = brev9(r);
    sre[rr * 9 + c] = v.x; sim[rr * 9 + c] = v.y;
  }
  fft512x8_tw<1>(sre, sim, tw, t >> 5, t & 31);
  float* Lb = L + (((size_t)b) << 18);
  #pragma unroll
  for (int it = 0; it < 16; ++it) {
    int r = (it << 5) + q;
    float re = sre[r * 9 + c], im = sim[r * 9 + c];
    Cb[r * W + col0 + c] = make_float2(re, im);
    Lb[r * W + col0 + c] = logf(sqrtf(fmaf(re, re, im * im)) + 1e-8f);
  }
}

// Build G = exp(resid) * e^{i*phase} = C * exp(resid)/|C| inline, then inverse row FFT.
__global__ void k_rowifft_g(float2* __restrict__ C, const float* __restrict__ L) {
  int r = blockIdx.x, b = blockIdx.y, t = threadIdx.x;
  __shared__ float sre[512], sim[512], l0[512], lm[512], lp[512];
  __shared__ float2 tw[256];
  tw_init(tw, t);
  const float* Lb = L + (((size_t)b) << 18);
  #pragma unroll
  for (int k = t; k < 512; k += 256) {
    l0[k] = Lb[r * W + k];
    lm[k] = (r > 0) ? Lb[(r - 1) * W + k] : 0.f;
    lp[k] = (r < H - 1) ? Lb[(r + 1) * W + k] : 0.f;
  }
  __syncthreads();
  float2* Crow = C + (((size_t)b) << 18) + r * W;
  #pragma unroll
  for (int k = t; k < 512; k += 256) {
    float sum = lm[k] + l0[k] + lp[k];
    if (k > 0)     sum += lm[k - 1] + l0[k - 1] + lp[k - 1];
    if (k < W - 1) sum += lm[k + 1] + l0[k + 1] + lp[k + 1];
    float resid = l0[k] - sum * (1.f / 9.f);
    float2 cv = Crow[k];
    float mag = sqrtf(fmaf(cv.x, cv.x, cv.y * cv.y));
    float er = __expf(resid);
    float gr, gi;
    if (mag > 1e-30f) { float tt = er / mag; gr = cv.x * tt; gi = cv.y * tt; }
    else { gr = er; gi = 0.f; }  // angle(0)=0 per reference
    int kr = brev9(k);
    sre[kr] = gr; sim[kr] = gi;
  }
  fft512_tw<-1>(sre, sim, tw, t);
  #pragma unroll
  for (int k = t; k < 512; k += 256)
    Crow[k] = make_float2(sre[k] * (1.f / 512.f), sim[k] * (1.f / 512.f));
}

// Inverse column FFT + sal=|.|^2 epilogue straight to out channel 0 + min/max.
__global__ void k_colifft_sal(const float2* __restrict__ C, float* __restrict__ out, unsigned* mm) {
  int b = blockIdx.y, col0 = blockIdx.x << 3, t = threadIdx.x;
  __shared__ float sre[512 * 9], sim[512 * 9];
  __shared__ float2 tw[256];
  tw_init(tw, t);
  const float2* Cb = C + (((size_t)b) << 18);
  int c = t & 7, q = t >> 3;
  #pragma unroll
  for (int it = 0; it < 16; ++it) {
    int r = (it << 5) + q;
    float2 v = Cb[r * W + col0 + c];
    int rr = brev9(r);
    sre[rr * 9 + c] = v.x; sim[rr * 9 + c] = v.y;
  }
  fft512x8_tw<-1>(sre, sim, tw, t >> 5, t & 31);
  float* ob = out + (((size_t)(b * 3 + 0)) << 18);
  float mn = INFINITY, mx = -INFINITY;
  #pragma unroll
  for (int it = 0; it < 16; ++it) {
    int r = (it << 5) + q;
    float re = sre[r * 9 + c], im = sim[r * 9 + c];
    // row pass carried 1/512; this pass contributes the other 1/512 -> (1/512)^2 on |.|^2
    float sal = fmaf(re, re, im * im) * 3.814697265625e-6f;
    ob[r * W + col0 + c] = sal;
    mn = fminf(mn, sal); mx = fmaxf(mx, sal);
  }
  block_minmax_atomic(mn, mx, mm + b * 3, mm + 48 + b * 3);
}

__global__ void k_norm(float* __restrict__ out, const unsigned* __restrict__ mm) {
  int i = blockIdx.x * blockDim.x + threadIdx.x;  // 0..3145727
  size_t base = ((size_t)i) << 2;
  int map = (int)(base >> 18);                    // 0..47 == b*3+ch
  float mn = __uint_as_float(mm[map]);
  float mx = __uint_as_float(mm[48 + map]);
  float rng = mx - mn;
  float4 v = *(float4*)(out + base);
  float4 o;
  if (rng < 1e-8f) {
    o = make_float4(0.f, 0.f, 0.f, 0.f);
  } else {
    float inv = 1.f / rng;
    o.x = (v.x - mn) * inv;
    o.y = (v.y - mn) * inv;
    o.z = (v.z - mn) * inv;
    o.w = (v.w - mn) * inv;
  }
  *(float4*)(out + base) = o;
}

extern "C" void kernel_launch(void* const* d_in, const int* in_sizes, int n_in,
                              void* d_out, int out_size, void* d_ws, size_t ws_size,
                              hipStream_t stream) {
  const float* x = (const float*)d_in[0];
  float* out = (float*)d_out;

  // workspace layout: gray (16.8MB) | C complex (33.6MB) | L logmag (16.8MB) | minmax (384B)
  float* gray = (float*)d_ws;
  float2* C = (float2*)((char*)d_ws + (size_t)NB * HW * sizeof(float));
  float* L = (float*)((char*)C + (size_t)NB * HW * sizeof(float2));
  unsigned* mm = (unsigned*)((char*)L + (size_t)NB * HW * sizeof(float));

  k_init<<<1, 96, 0, stream>>>(mm);
  k_rowfft<<<dim3(H, NB), 256, 0, stream>>>(x, gray, C);   // fused gray + row FFT
  k_ch12<<<dim3(16, NB), 256, 0, stream>>>(gray, out, mm);
  k_colfft_fwd<<<dim3(W / 8, NB), 256, 0, stream>>>(C, L);
  k_rowifft_g<<<dim3(H, NB), 256, 0, stream>>>(C, L);
  k_colifft_sal<<<dim3(W / 8, NB), 256, 0, stream>>>(C, out, mm);
  k_norm<<<12288, 256, 0, stream>>>(out, mm);
}

// Round 7
// 226.671 us; speedup vs baseline: 1.6439x; 1.0301x over previous
//
#include <hip/hip_runtime.h>
#include <hip/hip_bf16.h>
#include <math.h>

#define W 512
#define H 512
#define HW 262144
#define NB 16

__device__ __forceinline__ int brev9(int x) { return (int)(__brev((unsigned)x) >> 23); }
// pitch-17 pad: spreads quad strides (4/16/64/256 floats) across banks (~2-way max)
__device__ __forceinline__ int pad17(int i) { return i + (i >> 4); }

// Block-wide min/max reduce + device-scope uint atomics (nonneg floats only).
__device__ __forceinline__ void block_minmax_atomic(float vmin, float vmax,
                                                    unsigned* minU, unsigned* maxU) {
  #pragma unroll
  for (int o = 32; o; o >>= 1) {
    vmin = fminf(vmin, __shfl_xor(vmin, o));
    vmax = fmaxf(vmax, __shfl_xor(vmax, o));
  }
  __shared__ float smin[4], smax[4];
  int wid = threadIdx.x >> 6;
  int lane = threadIdx.x & 63;
  if (lane == 0) { smin[wid] = vmin; smax[wid] = vmax; }
  __syncthreads();
  if (threadIdx.x == 0) {
    int nw = (blockDim.x + 63) >> 6;
    float m = smin[0], M = smax[0];
    for (int i = 1; i < nw; ++i) { m = fminf(m, smin[i]); M = fmaxf(M, smax[i]); }
    atomicMin(minU, __float_as_uint(m));
    atomicMax(maxU, __float_as_uint(M));
  }
  __syncthreads();
}

__global__ void k_init(unsigned* mm) {
  int t = threadIdx.x;
  if (t < 48) mm[t] = 0x7F800000u;      // min slots = +inf
  else if (t < 96) mm[t] = 0u;          // max slots = 0 (all maps nonneg)
}

__device__ __forceinline__ float gray_one(float r, float g, float b) {
  float R = fminf(fmaxf(fmaf(r, 0.229f, 0.485f), 0.f), 1.f) * 255.f;
  float G = fminf(fmaxf(fmaf(g, 0.224f, 0.456f), 0.f), 1.f) * 255.f;
  float B = fminf(fmaxf(fmaf(b, 0.225f, 0.406f), 0.f), 1.f) * 255.f;
  return fmaf(0.299f, R, fmaf(0.587f, G, 0.114f * B));
}

// tw[k] = (cos,sin)(-2*pi*k/512), k=0..255. Visibility via barrier in FFT stage 1.
__device__ __forceinline__ void tw_init(float2* tw, int t, int nthr) {
  for (int k = t; k < 256; k += nthr) {
    float sn, cs;
    __sincosf(-6.283185307179586f * (float)k * (1.f / 512.f), &sn, &cs);
    tw[k] = make_float2(cs, sn);
  }
}

// Radix-2^2 butterfly core: two fused radix-2 stages (s=sp, sp+1), bit-identical
// to executing them separately. e0..e3 at indices q, q+h, q+2h, q+3h; h=2^(sp-1).
#define QUAD_BODY(LOADA0, LOADA1, LOADA2, LOADA3)                                   \
  float e0r = sre[LOADA0], e0i = sim[LOADA0];                                       \
  float e1r = sre[LOADA1], e1i = sim[LOADA1];                                       \
  float e2r = sre[LOADA2], e2i = sim[LOADA2];                                       \
  float e3r = sre[LOADA3], e3i = sim[LOADA3];                                       \
  float t1r = fmaf(e1r, w1c, -e1i * w1s), t1i = fmaf(e1r, w1s, e1i * w1c);          \
  float t3r = fmaf(e3r, w1c, -e3i * w1s), t3i = fmaf(e3r, w1s, e3i * w1c);          \
  float A0r = e0r + t1r, A0i = e0i + t1i;                                           \
  float A1r = e0r - t1r, A1i = e0i - t1i;                                           \
  float A2r = e2r + t3r, A2i = e2i + t3i;                                           \
  float A3r = e2r - t3r, A3i = e2i - t3i;                                           \
  float t2r = fmaf(A2r, w2c, -A2i * w2s), t2i = fmaf(A2r, w2s, A2i * w2c);          \
  float t4r = fmaf(A3r, w3c, -A3i * w3s), t4i = fmaf(A3r, w3s, A3i * w3c);          \
  sre[LOADA0] = A0r + t2r; sim[LOADA0] = A0i + t2i;                                 \
  sre[LOADA2] = A0r - t2r; sim[LOADA2] = A0i - t2i;                                 \
  sre[LOADA1] = A1r + t4r; sim[LOADA1] = A1i + t4i;                                 \
  sre[LOADA3] = A1r - t4r; sim[LOADA3] = A1i - t4i;

// 512-pt FFT, one row, 128 threads, pitch-17 padded LDS (input bit-reversed via
// pad17(brev9(k)); output read back at pad17(k)). 4 fused rounds + final radix-2.
template <int DIR>
__device__ __forceinline__ void fft512_q(float* sre, float* sim, const float2* tw, int t) {
  #pragma unroll
  for (int sp = 1; sp <= 7; sp += 2) {
    __syncthreads();
    int h = 1 << (sp - 1);
    int j = t & (h - 1);
    int q = ((t >> (sp - 1)) << (sp + 1)) + j;
    float2 w1t = tw[j << (9 - sp)];
    float2 w2t = tw[j << (8 - sp)];
    float2 w3t = tw[(j + h) << (8 - sp)];
    float w1c = w1t.x, w1s = (DIR > 0) ? w1t.y : -w1t.y;
    float w2c = w2t.x, w2s = (DIR > 0) ? w2t.y : -w2t.y;
    float w3c = w3t.x, w3s = (DIR > 0) ? w3t.y : -w3t.y;
    int a0 = pad17(q), a1 = pad17(q + h), a2 = pad17(q + 2 * h), a3 = pad17(q + 3 * h);
    QUAD_BODY(a0, a1, a2, a3)
  }
  __syncthreads();
  #pragma unroll
  for (int bb = 0; bb < 2; ++bb) {          // stage 9 (radix-2, span 512)
    int bf = t + (bb << 7);
    float2 w = tw[bf];
    float cs = w.x, sn = (DIR > 0) ? w.y : -w.y;
    int a0 = pad17(bf), a1 = pad17(bf + 256);
    float ur = sre[a0], ui = sim[a0];
    float vr = sre[a1], vi = sim[a1];
    float tr = fmaf(vr, cs, -vi * sn);
    float ti = fmaf(vr, sn, vi * cs);
    sre[a0] = ur + tr; sim[a0] = ui + ti;
    sre[a1] = ur - tr; sim[a1] = ui - ti;
  }
  __syncthreads();
}

// 8 columns per block (pitch 9), 32 threads/column, 4 quads/thread/round.
template <int DIR>
__device__ __forceinline__ void fft512x8_q(float* sre, float* sim, const float2* tw,
                                           int c, int tc) {
  #pragma unroll
  for (int sp = 1; sp <= 7; sp += 2) {
    __syncthreads();
    int h = 1 << (sp - 1);
    #pragma unroll
    for (int m = 0; m < 4; ++m) {
      int qq = tc + (m << 5);               // quad id 0..127
      int j = qq & (h - 1);
      int q = ((qq >> (sp - 1)) << (sp + 1)) + j;
      float2 w1t = tw[j << (9 - sp)];
      float2 w2t = tw[j << (8 - sp)];
      float2 w3t = tw[(j + h) << (8 - sp)];
      float w1c = w1t.x, w1s = (DIR > 0) ? w1t.y : -w1t.y;
      float w2c = w2t.x, w2s = (DIR > 0) ? w2t.y : -w2t.y;
      float w3c = w3t.x, w3s = (DIR > 0) ? w3t.y : -w3t.y;
      int a0 = q * 9 + c, a1 = (q + h) * 9 + c, a2 = (q + 2 * h) * 9 + c, a3 = (q + 3 * h) * 9 + c;
      QUAD_BODY(a0, a1, a2, a3)
    }
  }
  __syncthreads();
  #pragma unroll
  for (int bb = 0; bb < 8; ++bb) {          // stage 9
    int bf = tc + (bb << 5);
    float2 w = tw[bf];
    float cs = w.x, sn = (DIR > 0) ? w.y : -w.y;
    int a0 = bf * 9 + c, a1 = (bf + 256) * 9 + c;
    float ur = sre[a0], ui = sim[a0];
    float vr = sre[a1], vi = sim[a1];
    float tr = fmaf(vr, cs, -vi * sn);
    float ti = fmaf(vr, sn, vi * cs);
    sre[a0] = ur + tr; sim[a0] = ui + ti;
    sre[a1] = ur - tr; sim[a1] = ui - ti;
  }
  __syncthreads();
}

// Fused: gray conversion + row forward FFT. 128 threads per row.
__global__ void k_rowfft(const float* __restrict__ x, float* __restrict__ gray,
                         float2* __restrict__ C) {
  int r = blockIdx.x, b = blockIdx.y, t = threadIdx.x;
  __shared__ float sre[544], sim[544];
  __shared__ float2 tw[256];
  tw_init(tw, t, 128);
  const float* xr = x + (((size_t)(b * 3 + 0)) << 18) + r * W;
  const float* xg = x + (((size_t)(b * 3 + 1)) << 18) + r * W;
  const float* xb = x + (((size_t)(b * 3 + 2)) << 18) + r * W;
  float* gr = gray + (((size_t)b) << 18) + r * W;
  #pragma unroll
  for (int k = t; k < 512; k += 128) {
    float g = gray_one(xr[k], xg[k], xb[k]);
    gr[k] = g;
    int kr = pad17(brev9(k));
    sre[kr] = g; sim[kr] = 0.f;
  }
  fft512_q<1>(sre, sim, tw, t);
  float2* Crow = C + (((size_t)b) << 18) + r * W;
  #pragma unroll
  for (int k = t; k < 512; k += 128) {
    int kp = pad17(k);
    Crow[k] = make_float2(sre[kp], sim[kp]);
  }
}

// Channels 1 (|laplacian|, zero-pad) and 2 (blockiness, wrap roll), fused.
__global__ void k_ch12(const float* __restrict__ gray, float* __restrict__ out, unsigned* mm) {
  int slab = blockIdx.x, b = blockIdx.y, t = threadIdx.x;
  const float* gb = gray + (((size_t)b) << 18);
  float* o1 = out + (((size_t)(b * 3 + 1)) << 18);
  float* o2 = out + (((size_t)(b * 3 + 2)) << 18);
  float mn1 = INFINITY, mx1 = -INFINITY, mn2 = INFINITY, mx2 = -INFINITY;
  for (int i4 = t; i4 < 32 * 128; i4 += 256) {
    int r = (slab << 5) + (i4 >> 7);
    int k4 = (i4 & 127) << 2;
    const float* row = gb + r * W;
    float4 c4 = *(const float4*)(row + k4);
    float s_lfw = row[(k4 + W - 1) & (W - 1)];
    float s_rt  = (k4 < W - 4) ? row[k4 + 4] : 0.f;
    float4 up4 = (r > 0)     ? *(const float4*)(gb + (r - 1) * W + k4) : make_float4(0.f, 0.f, 0.f, 0.f);
    float4 dn4 = (r < H - 1) ? *(const float4*)(gb + (r + 1) * W + k4) : make_float4(0.f, 0.f, 0.f, 0.f);
    float c[4]  = {c4.x, c4.y, c4.z, c4.w};
    float up[4] = {up4.x, up4.y, up4.z, up4.w};
    float dn[4] = {dn4.x, dn4.y, dn4.z, dn4.w};
    float lap[4], blk[4];
    #pragma unroll
    for (int e = 0; e < 4; ++e) {
      float lf = (e == 0) ? ((k4 > 0) ? s_lfw : 0.f) : c[e - 1];
      float rt = (e == 3) ? s_rt : c[e + 1];
      lap[e] = fabsf(lf + rt + up[e] + dn[e] - 4.f * c[e]);
      mn1 = fminf(mn1, lap[e]); mx1 = fmaxf(mx1, lap[e]);
    }
    bool rowb = ((r & 7) == 0);
    float pv[4] = {0.f, 0.f, 0.f, 0.f};
    if (rowb) {
      int rp = (r + H - 1) & (H - 1);
      float4 p4 = *(const float4*)(gb + rp * W + k4);
      pv[0] = p4.x; pv[1] = p4.y; pv[2] = p4.z; pv[3] = p4.w;
    }
    #pragma unroll
    for (int e = 0; e < 4; ++e) {
      float v = 0.f;
      if (e == 0 && ((k4 & 7) == 0)) v += fabsf(c[0] - s_lfw);
      if (rowb) v += fabsf(c[e] - pv[e]);
      blk[e] = v;
      mn2 = fminf(mn2, v); mx2 = fmaxf(mx2, v);
    }
    *(float4*)(o1 + r * W + k4) = make_float4(lap[0], lap[1], lap[2], lap[3]);
    *(float4*)(o2 + r * W + k4) = make_float4(blk[0], blk[1], blk[2], blk[3]);
  }
  block_minmax_atomic(mn1, mx1, mm + (b * 3 + 1), mm + 48 + (b * 3 + 1));
  block_minmax_atomic(mn2, mx2, mm + (b * 3 + 2), mm + 48 + (b * 3 + 2));
}

// Column forward FFT (in-place on C) + logmag epilogue.
__global__ void k_colfft_fwd(float2* __restrict__ C, float* __restrict__ L) {
  int b = blockIdx.y, col0 = blockIdx.x << 3, t = threadIdx.x;
  __shared__ float sre[512 * 9], sim[512 * 9];
  __shared__ float2 tw[256];
  tw_init(tw, t, 256);
  float2* Cb = C + (((size_t)b) << 18);
  int c = t & 7, q = t >> 3;
  #pragma unroll
  for (int it = 0; it < 16; ++it) {
    int r = (it << 5) + q;
    float2 v = Cb[r * W + col0 + c];
    int rr = brev9(r);
    sre[rr * 9 + c] = v.x; sim[rr * 9 + c] = v.y;
  }
  fft512x8_q<1>(sre, sim, tw, t >> 5, t & 31);
  float* Lb = L + (((size_t)b) << 18);
  #pragma unroll
  for (int it = 0; it < 16; ++it) {
    int r = (it << 5) + q;
    float re = sre[r * 9 + c], im = sim[r * 9 + c];
    Cb[r * W + col0 + c] = make_float2(re, im);
    Lb[r * W + col0 + c] = logf(sqrtf(fmaf(re, re, im * im)) + 1e-8f);
  }
}

// Build G = C * exp(resid)/|C| inline, then inverse row FFT. 128 threads.
__global__ void k_rowifft_g(float2* __restrict__ C, const float* __restrict__ L) {
  int r = blockIdx.x, b = blockIdx.y, t = threadIdx.x;
  __shared__ float sre[544], sim[544], l0[512], lm[512], lp[512];
  __shared__ float2 tw[256];
  tw_init(tw, t, 128);
  const float* Lb = L + (((size_t)b) << 18);
  #pragma unroll
  for (int k = t; k < 512; k += 128) {
    l0[k] = Lb[r * W + k];
    lm[k] = (r > 0) ? Lb[(r - 1) * W + k] : 0.f;
    lp[k] = (r < H - 1) ? Lb[(r + 1) * W + k] : 0.f;
  }
  __syncthreads();
  float2* Crow = C + (((size_t)b) << 18) + r * W;
  #pragma unroll
  for (int k = t; k < 512; k += 128) {
    float sum = lm[k] + l0[k] + lp[k];
    if (k > 0)     sum += lm[k - 1] + l0[k - 1] + lp[k - 1];
    if (k < W - 1) sum += lm[k + 1] + l0[k + 1] + lp[k + 1];
    float resid = l0[k] - sum * (1.f / 9.f);
    float2 cv = Crow[k];
    float mag = sqrtf(fmaf(cv.x, cv.x, cv.y * cv.y));
    float er = __expf(resid);
    float gr, gi;
    if (mag > 1e-30f) { float tt = er / mag; gr = cv.x * tt; gi = cv.y * tt; }
    else { gr = er; gi = 0.f; }  // angle(0)=0 per reference
    int kr = pad17(brev9(k));
    sre[kr] = gr; sim[kr] = gi;
  }
  fft512_q<-1>(sre, sim, tw, t);
  #pragma unroll
  for (int k = t; k < 512; k += 128) {
    int kp = pad17(k);
    Crow[k] = make_float2(sre[kp] * (1.f / 512.f), sim[kp] * (1.f / 512.f));
  }
}

// Inverse column FFT + sal=|.|^2 epilogue to out channel 0 + min/max.
__global__ void k_colifft_sal(const float2* __restrict__ C, float* __restrict__ out, unsigned* mm) {
  int b = blockIdx.y, col0 = blockIdx.x << 3, t = threadIdx.x;
  __shared__ float sre[512 * 9], sim[512 * 9];
  __shared__ float2 tw[256];
  tw_init(tw, t, 256);
  const float2* Cb = C + (((size_t)b) << 18);
  int c = t & 7, q = t >> 3;
  #pragma unroll
  for (int it = 0; it < 16; ++it) {
    int r = (it << 5) + q;
    float2 v = Cb[r * W + col0 + c];
    int rr = brev9(r);
    sre[rr * 9 + c] = v.x; sim[rr * 9 + c] = v.y;
  }
  fft512x8_q<-1>(sre, sim, tw, t >> 5, t & 31);
  float* ob = out + (((size_t)(b * 3 + 0)) << 18);
  float mn = INFINITY, mx = -INFINITY;
  #pragma unroll
  for (int it = 0; it < 16; ++it) {
    int r = (it << 5) + q;
    float re = sre[r * 9 + c], im = sim[r * 9 + c];
    float sal = fmaf(re, re, im * im) * 3.814697265625e-6f;  // (1/512)^2 on |.|^2
    ob[r * W + col0 + c] = sal;
    mn = fminf(mn, sal); mx = fmaxf(mx, sal);
  }
  block_minmax_atomic(mn, mx, mm + b * 3, mm + 48 + b * 3);
}

__global__ void k_norm(float* __restrict__ out, const unsigned* __restrict__ mm) {
  int i = blockIdx.x * blockDim.x + threadIdx.x;
  size_t base = ((size_t)i) << 2;
  int map = (int)(base >> 18);
  float mn = __uint_as_float(mm[map]);
  float mx = __uint_as_float(mm[48 + map]);
  float rng = mx - mn;
  float4 v = *(float4*)(out + base);
  float4 o;
  if (rng < 1e-8f) {
    o = make_float4(0.f, 0.f, 0.f, 0.f);
  } else {
    float inv = 1.f / rng;
    o.x = (v.x - mn) * inv;
    o.y = (v.y - mn) * inv;
    o.z = (v.z - mn) * inv;
    o.w = (v.w - mn) * inv;
  }
  *(float4*)(out + base) = o;
}

extern "C" void kernel_launch(void* const* d_in, const int* in_sizes, int n_in,
                              void* d_out, int out_size, void* d_ws, size_t ws_size,
                              hipStream_t stream) {
  const float* x = (const float*)d_in[0];
  float* out = (float*)d_out;

  // workspace: gray (16.8MB) | C (33.6MB) | L (16.8MB) | minmax (384B)
  float* gray = (float*)d_ws;
  float2* C = (float2*)((char*)d_ws + (size_t)NB * HW * sizeof(float));
  float* L = (float*)((char*)C + (size_t)NB * HW * sizeof(float2));
  unsigned* mm = (unsigned*)((char*)L + (size_t)NB * HW * sizeof(float));

  k_init<<<1, 96, 0, stream>>>(mm);
  k_rowfft<<<dim3(H, NB), 128, 0, stream>>>(x, gray, C);
  k_ch12<<<dim3(16, NB), 256, 0, stream>>>(gray, out, mm);
  k_colfft_fwd<<<dim3(W / 8, NB), 256, 0, stream>>>(C, L);
  k_rowifft_g<<<dim3(H, NB), 128, 0, stream>>>(C, L);
  k_colifft_sal<<<dim3(W / 8, NB), 256, 0, stream>>>(C, out, mm);
  k_norm<<<12288, 256, 0, stream>>>(out, mm);
}